// Round 1
// baseline (1953.675 us; speedup 1.0000x reference)
//
#include <hip/hip_runtime.h>
#include <cstdint>
#include <math.h>

typedef unsigned int u32;
typedef unsigned long long u64;

// ---------------- geometry ----------------
// base_feature_map (8, 512, 50, 50); conv 3x3 SAME -> relu -> 1x1 heads
// anchors 50*50*9 = 22500; PRE_NMS 6000; POST_NMS 300
#define N_BATCH 8
#define C_IN    512
#define PX      2500     // 50*50
#define KDIM    4608     // 512*9
#define NA      22500
#define PRE_NMS 6000
#define POST_NMS 300

// d_out float layout (reference tuple concatenated):
// rpn_locs   [8][22500][4]  @ 0        (720000)
// rpn_scores [8][22500][2]  @ 720000   (360000)
// anchors    [22500][4]     @ 1080000  (90000)
// rois       [300][4]       @ 1170000  (1200)
#define OUT_SCORES 720000
#define OUT_ANCH   1080000
#define OUT_ROIS   1170000

// ws layout (float offsets)
#define WS_X     0            // x: 8*512*2500 = 10,240,000 floats
#define WS_SCORE 10240000     // 22500
#define WS_BOX   10262500     // 22500*4
#define WS_LIST  10352500     // u64[6000] (12000 floats, 8B aligned)
#define WS_CAND  10364500     // 6000*4
#define WS_META  10388500     // ints

// =================== conv3x3 + bias + relu (implicit GEMM) ===================
// tile: 128 co x 128 px, KB=32, 256 threads, 8x8 register tile
__global__ __launch_bounds__(256) void k_conv3(const float* __restrict__ in,
                                               const float* __restrict__ Wc,
                                               const float* __restrict__ bc,
                                               float* __restrict__ xout) {
    __shared__ float As[32][132];
    __shared__ float Bs[32][132];
    int b  = blockIdx.x;
    int cb = b & 3;            // co tile (4)
    int pt = (b >> 2) % 20;    // px tile (20)
    int n  = b / 80;           // batch
    int t  = threadIdx.x;
    int tx = t & 15, ty = t >> 4;
    int px0 = pt * 128, co0 = cb * 128;
    const float* inN = in + (size_t)n * C_IN * PX;

    float acc[8][8];
#pragma unroll
    for (int i = 0; i < 8; ++i)
#pragma unroll
        for (int j = 0; j < 8; ++j) acc[i][j] = 0.f;

    for (int k0 = 0; k0 < KDIM; k0 += 32) {
        // A: W[co0..co0+128][k0..k0+32]  (thread: co=t>>1, 16 k's)
        {
            int co  = t >> 1;
            int kkb = (t & 1) << 4;
            const float* wp = Wc + (size_t)(co0 + co) * KDIM + k0 + kkb;
#pragma unroll
            for (int q = 0; q < 4; ++q) {
                float4 w = *(const float4*)(wp + q * 4);
                As[kkb + q * 4 + 0][co] = w.x;
                As[kkb + q * 4 + 1][co] = w.y;
                As[kkb + q * 4 + 2][co] = w.z;
                As[kkb + q * 4 + 3][co] = w.w;
            }
        }
        // B: im2col gather [32 k][128 px]
        {
            int pxl = t & 127;
            int kk0 = (t >> 7) << 4;
            int px  = px0 + pxl;
            int y   = px / 50, x = px - y * 50;
#pragma unroll
            for (int it = 0; it < 16; ++it) {
                int kk = kk0 + it;
                int k  = k0 + kk;
                int ci = k / 9;
                int r  = k - ci * 9;
                int ky = r / 3;
                int kx = r - ky * 3;
                float v = 0.f;
                if (px < PX) {
                    int iy = y + ky - 1, ix = x + kx - 1;
                    if ((unsigned)iy < 50u && (unsigned)ix < 50u)
                        v = inN[ci * PX + iy * 50 + ix];
                }
                Bs[kk][pxl] = v;
            }
        }
        __syncthreads();
#pragma unroll 8
        for (int kk = 0; kk < 32; ++kk) {
            float a[8], bb[8];
            *(float4*)&a[0]  = *(const float4*)&As[kk][ty * 8];
            *(float4*)&a[4]  = *(const float4*)&As[kk][ty * 8 + 4];
            *(float4*)&bb[0] = *(const float4*)&Bs[kk][tx * 8];
            *(float4*)&bb[4] = *(const float4*)&Bs[kk][tx * 8 + 4];
#pragma unroll
            for (int i = 0; i < 8; ++i)
#pragma unroll
                for (int j = 0; j < 8; ++j)
                    acc[i][j] = fmaf(a[i], bb[j], acc[i][j]);
        }
        __syncthreads();
    }
    int pxb = px0 + tx * 8;
#pragma unroll
    for (int i = 0; i < 8; ++i) {
        int co = co0 + ty * 8 + i;
        float bias = bc[co];
        float v[8];
#pragma unroll
        for (int j = 0; j < 8; ++j) v[j] = fmaxf(acc[i][j] + bias, 0.f);
        float* dst = xout + ((size_t)n * C_IN + co) * PX + pxb;
        if (pxb + 8 <= PX) {
            *(float4*)dst       = make_float4(v[0], v[1], v[2], v[3]);
            *(float4*)(dst + 4) = make_float4(v[4], v[5], v[6], v[7]);
        } else {
            for (int j = 0; j < 8; ++j)
                if (pxb + j < PX) dst[j] = v[j];
        }
    }
}

// =================== 1x1 heads: 54(=36 reg + 18 cls) x 512 GEMM ===================
// tile: 64 co x 128 px, KB=32, 256 threads, 4x8 register tile
__global__ __launch_bounds__(256) void k_heads(const float* __restrict__ x,
                                               const float* __restrict__ Wreg,
                                               const float* __restrict__ breg,
                                               const float* __restrict__ Wcls,
                                               const float* __restrict__ bcls,
                                               float* __restrict__ out) {
    __shared__ float As[32][68];
    __shared__ float Bs[32][132];
    int b  = blockIdx.x;
    int pt = b % 20, n = b / 20;
    int t  = threadIdx.x;
    int tx = t & 15, ty = t >> 4;
    int px0 = pt * 128;
    float acc[4][8];
#pragma unroll
    for (int i = 0; i < 4; ++i)
#pragma unroll
        for (int j = 0; j < 8; ++j) acc[i][j] = 0.f;

    for (int k0 = 0; k0 < 512; k0 += 32) {
        {
            int c   = t >> 2;
            int kkb = (t & 3) << 3;
            const float* src = nullptr;
            if (c < 36)      src = Wreg + (size_t)c * 512 + k0 + kkb;
            else if (c < 54) src = Wcls + (size_t)(c - 36) * 512 + k0 + kkb;
#pragma unroll
            for (int q = 0; q < 2; ++q) {
                float4 w = src ? *(const float4*)(src + q * 4) : make_float4(0, 0, 0, 0);
                As[kkb + q * 4 + 0][c] = w.x;
                As[kkb + q * 4 + 1][c] = w.y;
                As[kkb + q * 4 + 2][c] = w.z;
                As[kkb + q * 4 + 3][c] = w.w;
            }
        }
        {
            int pxl = t & 127;
            int kk0 = (t >> 7) << 4;
            int px  = px0 + pxl;
#pragma unroll
            for (int it = 0; it < 16; ++it) {
                int kk = kk0 + it;
                float v = 0.f;
                if (px < PX) v = x[((size_t)n * 512 + k0 + kk) * PX + px];
                Bs[kk][pxl] = v;
            }
        }
        __syncthreads();
#pragma unroll 8
        for (int kk = 0; kk < 32; ++kk) {
            float a[4], bb[8];
            *(float4*)&a[0]  = *(const float4*)&As[kk][ty * 4];
            *(float4*)&bb[0] = *(const float4*)&Bs[kk][tx * 8];
            *(float4*)&bb[4] = *(const float4*)&Bs[kk][tx * 8 + 4];
#pragma unroll
            for (int i = 0; i < 4; ++i)
#pragma unroll
                for (int j = 0; j < 8; ++j)
                    acc[i][j] = fmaf(a[i], bb[j], acc[i][j]);
        }
        __syncthreads();
    }
    int pxb = px0 + tx * 8;
#pragma unroll
    for (int i = 0; i < 4; ++i) {
        int c = ty * 4 + i;
        if (c >= 54) continue;
        float bias = (c < 36) ? breg[c] : bcls[c - 36];
        for (int j = 0; j < 8; ++j) {
            int px = pxb + j;
            if (px >= PX) break;
            float v = acc[i][j] + bias;
            if (c < 36)
                out[(size_t)n * 90000 + (size_t)px * 36 + c] = v;
            else
                out[OUT_SCORES + (size_t)n * 45000 + (size_t)px * 18 + (c - 36)] = v;
        }
    }
}

// =================== anchors + decode (batch 0) ===================
__device__ inline float readDim(const void* p) {
    int v = *(const int*)p;
    if (v > 0 && v <= 100000) return (float)v;
    return *(const float*)p;
}

__global__ __launch_bounds__(256) void k_decode(float* __restrict__ dout,
                                                float* __restrict__ ws,
                                                const void* pih, const void* piw) {
    int idx = blockIdx.x * 256 + threadIdx.x;
    if (idx >= NA) return;
    float imgH = readDim(pih), imgW = readDim(piw);
    int a  = idx % 9;
    int px = idx / 9;
    int y = px / 50, x = px - y * 50;
    const float ratios[3] = {0.5f, 1.f, 2.f};
    const float scales[3] = {8.f, 16.f, 32.f};
    float r = ratios[a / 3], s = scales[a % 3];
    float hh = 16.f * s * sqrtf(r);
    float wv = 16.f * s * sqrtf(1.f / r);
    float ay1 = y * 16.f + 8.f - 0.5f * hh;
    float ax1 = x * 16.f + 8.f - 0.5f * wv;
    float ay2 = y * 16.f + 8.f + 0.5f * hh;
    float ax2 = x * 16.f + 8.f + 0.5f * wv;
    *(float4*)(dout + OUT_ANCH + (size_t)idx * 4) = make_float4(ay1, ax1, ay2, ax2);

    // decode batch 0
    float4 loc = *(const float4*)(dout + (size_t)idx * 4);
    float s0 = dout[OUT_SCORES + (size_t)idx * 2];
    float s1 = dout[OUT_SCORES + (size_t)idx * 2 + 1];
    float fg = 1.f / (1.f + expf(s0 - s1));
    float ah = ay2 - ay1, aw = ax2 - ax1;
    float acy = ay1 + 0.5f * ah, acx = ax1 + 0.5f * aw;
    float cy = loc.x * ah + acy;
    float cx = loc.y * aw + acx;
    float bh = expf(loc.z) * ah;
    float bw = expf(loc.w) * aw;
    float b0 = cy - 0.5f * bh, b1 = cx - 0.5f * bw;
    float b2 = cy + 0.5f * bh, b3 = cx + 0.5f * bw;
    b0 = fminf(fmaxf(b0, 0.f), imgH);
    b1 = fminf(fmaxf(b1, 0.f), imgW);
    b2 = fminf(fmaxf(b2, 0.f), imgH);
    b3 = fminf(fmaxf(b3, 0.f), imgW);
    bool valid = ((b2 - b0) >= 16.f) && ((b3 - b1) >= 16.f);
    ws[WS_SCORE + idx] = valid ? fg : -INFINITY;
    *(float4*)(ws + WS_BOX + (size_t)idx * 4) = make_float4(b0, b1, b2, b3);
}

// =================== top-6000 threshold + compaction (single block) ===================
__device__ inline u32 fkey(float s) {
    u32 u = __float_as_uint(s);
    return (u & 0x80000000u) ? ~u : (u | 0x80000000u);
}

__global__ __launch_bounds__(1024) void k_select(const float* __restrict__ score,
                                                 u64* __restrict__ list,
                                                 int* __restrict__ meta) {
    __shared__ u32 hist[4096];
    __shared__ int sB1, sB2, sB3, sM3, sNeed, sV;
    __shared__ u32 sT32;
    __shared__ int cHi, cTie;
    int t = threadIdx.x;
    const int NT = 1024;

    // ---- pass 1: top 12 bits ----
    for (int i = t; i < 4096; i += NT) hist[i] = 0;
    __syncthreads();
    for (int i = t; i < NA; i += NT) atomicAdd(&hist[fkey(score[i]) >> 20], 1u);
    __syncthreads();
    for (int off = 1; off < 4096; off <<= 1) {
        u32 v[4]; int c = 0;
        for (int bb = t; bb < 4096; bb += NT) { v[c++] = hist[bb] + ((bb + off < 4096) ? hist[bb + off] : 0u); }
        __syncthreads();
        c = 0;
        for (int bb = t; bb < 4096; bb += NT) hist[bb] = v[c++];
        __syncthreads();
    }
    for (int bb = t; bb < 4096; bb += NT) {
        u32 Sb  = hist[bb];
        u32 Sb1 = (bb < 4095) ? hist[bb + 1] : 0u;
        if (Sb >= PRE_NMS && Sb1 < PRE_NMS) sB1 = bb;
    }
    if (t == 0) sV = (int)hist[2048];   // count of finite (positive-float-key) scores
    __syncthreads();
    int B1 = sB1;
    int m1 = (B1 < 4095) ? (int)hist[B1 + 1] : 0;
    int V  = sV;
    __syncthreads();

    // ---- pass 2: mid 12 bits within bin B1 ----
    for (int i = t; i < 4096; i += NT) hist[i] = 0;
    __syncthreads();
    for (int i = t; i < NA; i += NT) {
        u32 key = fkey(score[i]);
        if ((int)(key >> 20) == B1) atomicAdd(&hist[(key >> 8) & 0xFFFu], 1u);
    }
    __syncthreads();
    for (int off = 1; off < 4096; off <<= 1) {
        u32 v[4]; int c = 0;
        for (int bb = t; bb < 4096; bb += NT) { v[c++] = hist[bb] + ((bb + off < 4096) ? hist[bb + off] : 0u); }
        __syncthreads();
        c = 0;
        for (int bb = t; bb < 4096; bb += NT) hist[bb] = v[c++];
        __syncthreads();
    }
    for (int bb = t; bb < 4096; bb += NT) {
        int Sb  = m1 + (int)hist[bb];
        int Sb1 = m1 + (int)((bb < 4095) ? hist[bb + 1] : 0u);
        if (Sb >= PRE_NMS && Sb1 < PRE_NMS) sB2 = bb;
    }
    __syncthreads();
    int B2 = sB2;
    int m2 = m1 + (int)((B2 < 4095) ? hist[B2 + 1] : 0u);
    u32 P24 = ((u32)B1 << 12) | (u32)B2;
    __syncthreads();

    // ---- pass 3: low 8 bits within 24-bit prefix ----
    for (int i = t; i < 256; i += NT) hist[i] = 0;
    __syncthreads();
    for (int i = t; i < NA; i += NT) {
        u32 key = fkey(score[i]);
        if ((key >> 8) == P24) atomicAdd(&hist[key & 0xFFu], 1u);
    }
    __syncthreads();
    for (int off = 1; off < 256; off <<= 1) {
        u32 v[1]; int c = 0;
        for (int bb = t; bb < 256; bb += NT) { v[c++] = hist[bb] + ((bb + off < 256) ? hist[bb + off] : 0u); }
        __syncthreads();
        c = 0;
        for (int bb = t; bb < 256; bb += NT) hist[bb] = v[c++];
        __syncthreads();
    }
    for (int bb = t; bb < 256; bb += NT) {
        int Sb  = m2 + (int)hist[bb];
        int Sb1 = m2 + (int)((bb < 255) ? hist[bb + 1] : 0u);
        if (Sb >= PRE_NMS && Sb1 < PRE_NMS) {
            sB3   = bb;
            sM3   = m2 + (int)((bb < 255) ? hist[bb + 1] : 0u);
            sNeed = PRE_NMS - sM3;
            sT32  = (P24 << 8) | (u32)bb;
        }
    }
    if (t == 0) { cHi = 0; cTie = 0; meta[0] = (V < PRE_NMS) ? V : PRE_NMS; }
    __syncthreads();
    int m3 = sM3, need = sNeed;
    u32 T32 = sT32;

    // ---- compaction: exactly 6000 entries ----
    for (int i = t; i < NA; i += NT) {
        u32 key = fkey(score[i]);
        u64 comp = ((u64)key << 32) | (u64)(0xFFFFFFFFu - (u32)i);
        if (key > T32) {
            int p = atomicAdd(&cHi, 1);
            list[p] = comp;
        } else if (key == T32) {
            int p = atomicAdd(&cTie, 1);
            if (p < need) list[m3 + p] = comp;
        }
    }
}

// =================== bitonic sort 8192 (desc) + gather cand boxes ===================
__global__ __launch_bounds__(1024) void k_sort(u64* __restrict__ list,
                                               const float* __restrict__ boxes,
                                               float* __restrict__ cand) {
    __shared__ u64 sb[8192];
    int t = threadIdx.x;
    for (int i = t; i < 8192; i += 1024) sb[i] = (i < PRE_NMS) ? list[i] : 0ull;
    __syncthreads();
    for (int k = 2; k <= 8192; k <<= 1) {
        for (int j = k >> 1; j > 0; j >>= 1) {
            for (int i = t; i < 8192; i += 1024) {
                int ixj = i ^ j;
                if (ixj > i) {
                    u64 a = sb[i], b = sb[ixj];
                    bool desc = ((i & k) == 0);
                    if (desc ? (a < b) : (a > b)) { sb[i] = b; sb[ixj] = a; }
                }
            }
            __syncthreads();
        }
    }
    for (int e = t; e < PRE_NMS; e += 1024) {
        u32 idx = 0xFFFFFFFFu - (u32)sb[e];
        float4 bx = *(const float4*)(boxes + (size_t)idx * 4);
        *(float4*)(cand + (size_t)e * 4) = bx;
    }
}

// =================== greedy NMS, early-exit at 300 survivors ===================
__global__ __launch_bounds__(256) void k_nms(const float* __restrict__ cand,
                                             const int* __restrict__ meta,
                                             float* __restrict__ rois) {
    __shared__ float kb[POST_NMS][4];
    __shared__ u64 supArr[4];
    int t = threadIdx.x;
    int lane = t & 63, wid = t >> 6;
    int keepN = meta[0];
    int kept = 0;

    for (int c0 = 0; c0 < PRE_NMS && kept < POST_NMS; c0 += 64) {
        int i = c0 + lane;
        float y1 = 0, x1 = 0, y2 = 0, x2 = 0;
        bool elig = (i < keepN);
        if (i < PRE_NMS) {
            float4 bx = *(const float4*)(cand + (size_t)i * 4);
            y1 = bx.x; x1 = bx.y; y2 = bx.z; x2 = bx.w;
        } else {
            elig = false;
        }
        float area = (y2 - y1) * (x2 - x1);

        // phase A: vs already-kept boxes, kept-list split across 4 waves
        bool supA = false;
        for (int jj = wid; jj < kept; jj += 4) {
            float ky1 = kb[jj][0], kx1 = kb[jj][1], ky2 = kb[jj][2], kx2 = kb[jj][3];
            float yy1 = fmaxf(ky1, y1), xx1 = fmaxf(kx1, x1);
            float yy2 = fminf(ky2, y2), xx2 = fminf(kx2, x2);
            float inter = fmaxf(yy2 - yy1, 0.f) * fmaxf(xx2 - xx1, 0.f);
            float karea = (ky2 - ky1) * (kx2 - kx1);
            float iou = inter / (karea + area - inter + 1e-12f);
            if (iou > 0.7f) { supA = true; break; }
        }
        supArr[wid] = __ballot(supA);
        __syncthreads();
        u64 sup = supArr[0] | supArr[1] | supArr[2] | supArr[3];
        u64 eligMask = __ballot(elig);

        // phase B: within-chunk greedy (all 4 waves compute identically)
        for (int s = 0; s < 64; ++s) {
            if (kept >= POST_NMS) break;
            if (!((eligMask >> s) & 1ull)) continue;
            if ((sup >> s) & 1ull) continue;
            // box s is kept
            float sy1 = __shfl(y1, s), sx1 = __shfl(x1, s);
            float sy2 = __shfl(y2, s), sx2 = __shfl(x2, s);
            float sar = __shfl(area, s);
            if (wid == 0 && lane == s) {
                kb[kept][0] = y1; kb[kept][1] = x1; kb[kept][2] = y2; kb[kept][3] = x2;
                *(float4*)(rois + (size_t)kept * 4) = make_float4(y1, x1, y2, x2);
            }
            float yy1 = fmaxf(sy1, y1), xx1 = fmaxf(sx1, x1);
            float yy2 = fminf(sy2, y2), xx2 = fminf(sx2, x2);
            float inter = fmaxf(yy2 - yy1, 0.f) * fmaxf(xx2 - xx1, 0.f);
            float iou = inter / (sar + area - inter + 1e-12f);
            bool kill = (lane > s) && (iou > 0.7f);
            sup |= __ballot(kill);
            kept++;
        }
        __syncthreads();
    }
    // zero-fill remaining rois
    for (int r = kept * 4 + t; r < POST_NMS * 4; r += 256) rois[r] = 0.f;
}

// =================== launcher ===================
extern "C" void kernel_launch(void* const* d_in, const int* in_sizes, int n_in,
                              void* d_out, int out_size, void* d_ws, size_t ws_size,
                              hipStream_t stream) {
    const float* feat = (const float*)d_in[0];
    const float* Wc   = (const float*)d_in[1];
    const float* bc   = (const float*)d_in[2];
    const float* Wcls = (const float*)d_in[3];
    const float* bcls = (const float*)d_in[4];
    const float* Wreg = (const float*)d_in[5];
    const float* breg = (const float*)d_in[6];
    const void* pih   = d_in[7];
    const void* piw   = d_in[8];
    float* out = (float*)d_out;
    float* ws  = (float*)d_ws;

    u64* list = (u64*)(ws + WS_LIST);
    int* meta = (int*)(ws + WS_META);

    hipLaunchKernelGGL(k_conv3, dim3(640), dim3(256), 0, stream, feat, Wc, bc, ws + WS_X);
    hipLaunchKernelGGL(k_heads, dim3(160), dim3(256), 0, stream, ws + WS_X, Wreg, breg, Wcls, bcls, out);
    hipLaunchKernelGGL(k_decode, dim3(88), dim3(256), 0, stream, out, ws, pih, piw);
    hipLaunchKernelGGL(k_select, dim3(1), dim3(1024), 0, stream, ws + WS_SCORE, list, meta);
    hipLaunchKernelGGL(k_sort, dim3(1), dim3(1024), 0, stream, list, ws + WS_BOX, ws + WS_CAND);
    hipLaunchKernelGGL(k_nms, dim3(1), dim3(256), 0, stream, ws + WS_CAND, meta, out + OUT_ROIS);
}